// Round 12
// baseline (108.014 us; speedup 1.0000x reference)
//
#include <hip/hip_runtime.h>

// CompoundClassifier, round 19: rolling-window edge pipeline (ILP + TLP).
//   P = x_ing @ W1[:128], Q = x_cmp @ W1[128:] + b1  -> fp8 tables (1 B/el)
//   out[e] = sigmoid( relu(P[s]+Q[d]) . W2 + b2 )
// r17/r18 post-mortem: full 16-pass arrays (si/di/pd/qd[16] ~160 VGPR) pushed
// the kernel to ~2 waves/SIMD — the deep pipeline TRADED TLP for ILP instead of
// adding. r19 keeps the same unrolled schedule + 4-ahead row prefetch but
// windows the registers: si/di[8], pd/qd[8] (~96 VGPR arrays, target <=128
// total -> 4 waves/SIMD, 2x r18 residency at same prefetch depth).
// Also pq_gemm NSTRIP 4->8 (235 blocks, bf amortized 8x; warm strips ~half
// cost per r12). f16 inner math (r18) kept.

#define H  128
#define NI 20000
#define NC 10000
#define NE 1000000

typedef _Float16 half8   __attribute__((ext_vector_type(8)));
typedef _Float16 half2   __attribute__((ext_vector_type(2)));
typedef float    floatx2 __attribute__((ext_vector_type(2)));
typedef float    floatx4 __attribute__((ext_vector_type(4)));

// ws byte layout
#define P8_OFF    0
#define Q8_OFF    (NI * H)                    // 2,560,000
// total ws use: 3,840,000 B (P8 + Q8)

#define PB (NI / 16)   // 1250 strips of P
#define QB (NC / 16)   // 625 strips of Q
#define NSTRIP 8
#define PBLKS ((PB + NSTRIP - 1) / NSTRIP)    // 157
#define QBLKS ((QB + NSTRIP - 1) / NSTRIP)    // 79

// ---------- fp8 e4m3 helpers (HW path on gfx950; SW fallback for safety) ----
#if __has_builtin(__builtin_amdgcn_cvt_pk_f32_fp8) && __has_builtin(__builtin_amdgcn_cvt_pk_fp8_f32)
#define HW_FP8 1
#else
#define HW_FP8 0
__device__ inline unsigned char enc_e4m3(float x) {
    unsigned s = x < 0.0f ? 0x80u : 0u;
    float a = fminf(fabsf(x), 448.0f);
    if (a < 0.0009765625f) return (unsigned char)s;       // < 2^-10 -> 0
    int e; float m = frexpf(a, &e);                       // a = m*2^e, m in [0.5,1)
    int E = e + 6;                                        // biased exp
    if (E <= 0) {                                         // subnormal: f*2^-9
        int f = (int)rintf(a * 512.0f);
        if (f > 7) return (unsigned char)(s | 0x08);
        return (unsigned char)(s | f);
    }
    int f = (int)rintf((m * 2.0f - 1.0f) * 8.0f);
    if (f == 8) { f = 0; ++E; }
    if (E > 15 || (E == 15 && f > 6)) { E = 15; f = 6; }  // clamp to 448
    return (unsigned char)(s | (E << 3) | f);
}
__device__ inline float dec_e4m3(unsigned char b) {
    int E = (b >> 3) & 15, f = b & 7;
    float v = (E == 0) ? (float)f * 0.001953125f          // f * 2^-9
                       : (float)(8 + f) * exp2f((float)(E - 10));
    return (b & 0x80) ? -v : v;
}
#endif

// f16 fast path: fp8->f16 packed decode + dot2 f16 MAC with f32 accumulate
#if HW_FP8 && __has_builtin(__builtin_amdgcn_cvt_pk_f16_fp8) && __has_builtin(__builtin_amdgcn_fdot2)
#define HW_F16 1
__device__ __forceinline__ half2 dec2h(short s) {
    auto t = __builtin_amdgcn_cvt_pk_f16_fp8(s);
    half2 r; __builtin_memcpy(&r, &t, sizeof(r)); return r;
}
__device__ __forceinline__ half2 hrelu2(half2 v) {
#if __has_builtin(__builtin_elementwise_max)
    half2 z = {(_Float16)0.0f, (_Float16)0.0f};
    return __builtin_elementwise_max(v, z);
#else
    half2 r = { v.x > (_Float16)0.0f ? v.x : (_Float16)0.0f,
                v.y > (_Float16)0.0f ? v.y : (_Float16)0.0f };
    return r;
#endif
}
#else
#define HW_F16 0
#endif

__device__ inline floatx2 relu2(floatx2 v) {
#if __has_builtin(__builtin_elementwise_max)
    floatx2 z = {0.0f, 0.0f};
    return __builtin_elementwise_max(v, z);
#else
    floatx2 r = { fmaxf(v.x, 0.0f), fmaxf(v.y, 0.0f) };
    return r;
#endif
}

__device__ __forceinline__ float fast_sigmoid(float x) {
#if __has_builtin(__builtin_amdgcn_exp2f) && __has_builtin(__builtin_amdgcn_rcpf)
    const float t = __builtin_amdgcn_exp2f(-1.4426950408889634f * x);
    return __builtin_amdgcn_rcpf(1.0f + t);
#else
    return 1.0f / (1.0f + __expf(-x));
#endif
}

// DPP-fused butterfly add over 8-lane groups (no LDS pipe, no lgkmcnt)
#if __has_builtin(__builtin_amdgcn_update_dpp)
template <int CTRL>
__device__ __forceinline__ float dpp_add(float x) {
    const int yi = __builtin_amdgcn_update_dpp(0, __float_as_int(x), CTRL, 0xf, 0xf, false);
    return x + __int_as_float(yi);
}
#define REDUCE8(ACC) do {                          \
        ACC = dpp_add<0xB1>(ACC);  /* quad_perm [1,0,3,2] : xor1 */        \
        ACC = dpp_add<0x4E>(ACC);  /* quad_perm [2,3,0,1] : xor2 */        \
        ACC = dpp_add<0x141>(ACC); /* row_half_mirror     : xor4 */        \
    } while (0)
#else
#define REDUCE8(ACC) do {                          \
        ACC += __shfl_xor(ACC, 1);                 \
        ACC += __shfl_xor(ACC, 2);                 \
        ACC += __shfl_xor(ACC, 4);                 \
    } while (0)
#endif

// ---------- P/Q precompute: direct W1 fragments, 8 strips/block ----------
__launch_bounds__(256)
__global__ void pq_gemm(const float* __restrict__ xin,
                        const float* __restrict__ xcmp,
                        const float* __restrict__ b1,
                        const float* __restrict__ W1,   // [256][128] row-major
                        unsigned char* __restrict__ wsb) {
    const int b    = blockIdx.x;
    const bool isQ = (b >= PBLKS);
    const int  sb  = isQ ? b - PBLKS : b;
    const int  s0  = sb * NSTRIP;                 // first strip of this block
    const int  smax = (isQ ? QB : PB) - 1;        // last valid strip
    const float* X = isQ ? xcmp : xin;
    unsigned char* OUT8 = wsb + (isQ ? Q8_OFF : P8_OFF);

    const int lane = threadIdx.x & 63;
    const int w    = threadIdx.x >> 6;
    const int quad = lane >> 4;
    const int m    = lane & 15;

    // B-fragments straight from W1, ONCE per block (amortized over 8 strips)
    half8 bf[2][4];
    float b1v[2];
#pragma unroll
    for (int nt = 0; nt < 2; ++nt) {
        const int n = w * 32 + nt * 16 + m;
#pragma unroll
        for (int ks = 0; ks < 4; ++ks) {
            const float* wp = W1 + (long)(isQ * 128 + ks * 32 + quad * 8) * H + n;
            half8 v;
#pragma unroll
            for (int j = 0; j < 8; ++j)
                v[j] = (_Float16)wp[j * H];
            bf[nt][ks] = v;
        }
        b1v[nt] = isQ ? b1[n] : 0.0f;
    }

#define LOADA(S, AF) do {                                                \
        const int _s = (S) > smax ? smax : (S);                          \
        const float* xr = X + (long)(_s * 16 + m) * H + quad * 8;        \
        _Pragma("unroll")                                                \
        for (int ks = 0; ks < 4; ++ks) {                                 \
            float4 a = *(const float4*)(xr + ks * 32);                   \
            float4 c = *(const float4*)(xr + ks * 32 + 4);               \
            half8 v = { (_Float16)a.x, (_Float16)a.y, (_Float16)a.z,     \
                        (_Float16)a.w, (_Float16)c.x, (_Float16)c.y,     \
                        (_Float16)c.z, (_Float16)c.w };                  \
            AF[ks] = v;                                                  \
        }                                                                \
    } while (0)

#if HW_FP8
#define EMIT8(PTR, V) do {                                               \
        const unsigned _u = (unsigned)__builtin_amdgcn_cvt_pk_fp8_f32((V), (V), 0, false); \
        *(unsigned char*)(PTR) = (unsigned char)(_u & 0xff);             \
    } while (0)
#else
#define EMIT8(PTR, V) do { *(unsigned char*)(PTR) = enc_e4m3(V); } while (0)
#endif

#define STRIPC(S, AF) do {                                               \
        floatx4 acc[2] = { (floatx4)0.0f, (floatx4)0.0f };               \
        _Pragma("unroll")                                                \
        for (int ks = 0; ks < 4; ++ks)                                   \
            _Pragma("unroll")                                            \
            for (int nt = 0; nt < 2; ++nt)                               \
                acc[nt] = __builtin_amdgcn_mfma_f32_16x16x32_f16(        \
                              AF[ks], bf[nt][ks], acc[nt], 0, 0, 0);     \
        if ((S) <= smax) {                                               \
            const int rb = (S) * 16;                                     \
            _Pragma("unroll")                                            \
            for (int nt = 0; nt < 2; ++nt) {                             \
                const int col = w * 32 + nt * 16 + m;                    \
                _Pragma("unroll")                                        \
                for (int r = 0; r < 4; ++r) {                            \
                    const float v = acc[nt][r] + b1v[nt];                \
                    EMIT8(OUT8 + (rb + quad * 4 + r) * H + col, v);      \
                }                                                        \
            }                                                            \
        }                                                                \
    } while (0)

    // ping-pong A fragments across 8 strips (prefetch s+1 during compute s)
    half8 afA[4], afB[4];
    LOADA(s0, afA);
    LOADA(s0 + 1, afB);
#pragma unroll
    for (int i = 0; i < 3; ++i) {
        STRIPC(s0 + 2 * i, afA);
        LOADA(s0 + 2 * i + 2, afA);
        STRIPC(s0 + 2 * i + 1, afB);
        LOADA(s0 + 2 * i + 3, afB);
    }
    STRIPC(s0 + 6, afA);
    STRIPC(s0 + 7, afB);

#undef LOADA
#undef STRIPC
#undef EMIT8
}

// ---------- edge kernel: rolling-window pipeline (depth-4 rows, idx 8 ahead) -
#define EGRID 2048
#define ESTEP (32 * EGRID)          // 65536 edges per device pass
// NE = 1,000,000 = 15 full passes (k=0..14) + tail pass k=15 (16,960 edges)

__launch_bounds__(256)
__global__ void edge_mlp(const unsigned char* __restrict__ wsb,
                         const int* __restrict__ src_idx,
                         const int* __restrict__ dst_idx,
                         const float* __restrict__ W2,
                         const float* __restrict__ b2p,
                         float* __restrict__ out) {
    const int tid  = threadIdx.x;
    const int c    = tid & 7;       // 16-byte slice of the 128-B row
    const int slot = tid >> 3;      // edge within block-pass (0..31)

    // W2 slice: 16 coefficients for cols c*16..c*16+15
#if HW_F16
    half2 w2h[8];
#pragma unroll
    for (int i = 0; i < 8; ++i) {
        floatx2 f = *(const floatx2*)(W2 + c * 16 + i * 2);
        half2 h = { (_Float16)f.x, (_Float16)f.y };
        w2h[i] = h;
    }
#else
    floatx2 w2v[8];
#pragma unroll
    for (int i = 0; i < 8; ++i) w2v[i] = *(const floatx2*)(W2 + c * 16 + i * 2);
#endif
    const float b2v = b2p[0];

    const unsigned char* P8 = wsb + P8_OFF;
    const unsigned char* Q8 = wsb + Q8_OFF;
    const int ebase = blockIdx.x * 32 + slot;   // < 65536

    // rolling windows: idx span 8 (load k+8, use at ISSUE k+4), rows span 8
    int  si[8], di[8];
    uint4 pd[8], qd[8];

    // idx load: only k=15 can run past NE (clamped; its store is masked)
#define LDIDX(K) do {                                                \
        int _e = ebase + (K) * ESTEP;                                \
        if ((K) == 15) _e = _e < NE ? _e : NE - 1;                   \
        si[(K) & 7] = __builtin_nontemporal_load(src_idx + _e);      \
        di[(K) & 7] = __builtin_nontemporal_load(dst_idx + _e);      \
    } while (0)

#define ISSUE(K) do {                                                \
        pd[(K) & 7] = *(const uint4*)(P8 + si[(K) & 7] * H + c * 16);\
        qd[(K) & 7] = *(const uint4*)(Q8 + di[(K) & 7] * H + c * 16);\
    } while (0)

#if HW_F16
#define INNER(PW, QW, JW, ACC) do {                                  \
        half2 pl = dec2h((short)(PW));                               \
        half2 ph = dec2h((short)((PW) >> 16));                       \
        half2 ql = dec2h((short)(QW));                               \
        half2 qh = dec2h((short)((QW) >> 16));                       \
        half2 hl = hrelu2(pl + ql);                                  \
        half2 hh = hrelu2(ph + qh);                                  \
        ACC = __builtin_amdgcn_fdot2(hl, w2h[2 * (JW)], ACC, false); \
        ACC = __builtin_amdgcn_fdot2(hh, w2h[2 * (JW) + 1], ACC, false); \
    } while (0)
#define COMPUTE(K) do {                                              \
        float acc = 0.0f;                                            \
        const unsigned pw[4] = { pd[(K) & 7].x, pd[(K) & 7].y,       \
                                 pd[(K) & 7].z, pd[(K) & 7].w };     \
        const unsigned qw[4] = { qd[(K) & 7].x, qd[(K) & 7].y,       \
                                 qd[(K) & 7].z, qd[(K) & 7].w };     \
        _Pragma("unroll")                                            \
        for (int jw = 0; jw < 4; ++jw)                               \
            INNER(pw[jw], qw[jw], jw, acc);                          \
        REDUCE8(acc);                                                \
        const float r = fast_sigmoid(acc + b2v);                     \
        const int _e = ebase + (K) * ESTEP;                          \
        if (c == 0 && ((K) < 15 || _e < NE))                         \
            __builtin_nontemporal_store(r, out + _e);                \
    } while (0)
#else
#if HW_FP8
#define DECODE(PW, QW, PL, PH, QL, QH) do {                          \
        PL = __builtin_amdgcn_cvt_pk_f32_fp8((int)(PW), false);      \
        PH = __builtin_amdgcn_cvt_pk_f32_fp8((int)(PW), true);       \
        QL = __builtin_amdgcn_cvt_pk_f32_fp8((int)(QW), false);      \
        QH = __builtin_amdgcn_cvt_pk_f32_fp8((int)(QW), true);       \
    } while (0)
#else
#define DECODE(PW, QW, PL, PH, QL, QH) do {                          \
        PL = { dec_e4m3((PW) & 0xff), dec_e4m3(((PW) >> 8) & 0xff) };  \
        PH = { dec_e4m3(((PW) >> 16) & 0xff), dec_e4m3((PW) >> 24) };  \
        QL = { dec_e4m3((QW) & 0xff), dec_e4m3(((QW) >> 8) & 0xff) };  \
        QH = { dec_e4m3(((QW) >> 16) & 0xff), dec_e4m3((QW) >> 24) };  \
    } while (0)
#endif
#define COMPUTE(K) do {                                              \
        floatx2 acc2 = {0.0f, 0.0f};                                 \
        const unsigned pw[4] = { pd[(K) & 7].x, pd[(K) & 7].y,       \
                                 pd[(K) & 7].z, pd[(K) & 7].w };     \
        const unsigned qw[4] = { qd[(K) & 7].x, qd[(K) & 7].y,       \
                                 qd[(K) & 7].z, qd[(K) & 7].w };     \
        _Pragma("unroll")                                            \
        for (int jw = 0; jw < 4; ++jw) {                             \
            floatx2 pl, ph, ql, qh;                                  \
            DECODE(pw[jw], qw[jw], pl, ph, ql, qh);                  \
            acc2 += relu2(pl + ql) * w2v[2 * jw];                    \
            acc2 += relu2(ph + qh) * w2v[2 * jw + 1];                \
        }                                                            \
        float acc = acc2.x + acc2.y;                                 \
        REDUCE8(acc);                                                \
        const float r = fast_sigmoid(acc + b2v);                     \
        const int _e = ebase + (K) * ESTEP;                          \
        if (c == 0 && ((K) < 15 || _e < NE))                         \
            __builtin_nontemporal_store(r, out + _e);                \
    } while (0)
#endif

    // ---- unrolled schedule with windowed registers ----
    // slot-reuse safety: LDIDX(k+8) overwrites idx slot consumed by ISSUE(k)
    // four iterations earlier; ISSUE(k+4) overwrites row slot consumed by
    // COMPUTE(k) in the SAME iteration -> COMPUTE first, then prefetches.
#pragma unroll
    for (int k = 0; k < 8; ++k) LDIDX(k);
#pragma unroll
    for (int k = 0; k < 4; ++k) ISSUE(k);
#pragma unroll
    for (int k = 0; k < 16; ++k) {
        COMPUTE(k);
        if (k + 4 < 16) ISSUE(k + 4);
        if (k + 8 < 16) LDIDX(k + 8);
    }

#undef LDIDX
#undef ISSUE
#undef COMPUTE
}

extern "C" void kernel_launch(void* const* d_in, const int* in_sizes, int n_in,
                              void* d_out, int out_size, void* d_ws, size_t ws_size,
                              hipStream_t stream) {
    const float* xin  = (const float*)d_in[0];
    const float* xcmp = (const float*)d_in[1];
    const int*   eidx = (const int*)d_in[2];    // [2,E]: first E src, next E dst
    const float* W1   = (const float*)d_in[3];
    const float* b1   = (const float*)d_in[4];
    const float* W2   = (const float*)d_in[5];
    const float* b2   = (const float*)d_in[6];
    float* out = (float*)d_out;
    unsigned char* wsb = (unsigned char*)d_ws;  // 3.84 MB used

    hipLaunchKernelGGL(pq_gemm, dim3(PBLKS + QBLKS), dim3(256), 0, stream,
                       xin, xcmp, b1, W1, wsb);
    hipLaunchKernelGGL(edge_mlp, dim3(EGRID), dim3(256), 0, stream,
                       wsb, eidx, eidx + NE, W2, b2, out);
}

// Round 13
// 107.936 us; speedup vs baseline: 1.0007x; 1.0007x over previous
//
#include <hip/hip_runtime.h>

// CompoundClassifier, round 20: REVERT to r18 (measured best, 106.97us).
//   P = x_ing @ W1[:128], Q = x_cmp @ W1[128:] + b1  -> fp8 tables (1 B/el)
//   out[e] = sigmoid( relu(P[s]+Q[d]) . W2 + b2 )
// r19 post-mortem: register windowing + NSTRIP=8 regressed (108.0 vs 107.0) —
// slot-rotation copies / strip-tail imbalance ate the occupancy gain. Per the
// r19 pre-commitment, mechanisms are exhausted; restoring the best state.
// Session budget (measured r10/r12): harness ws-poison fill ~46us (fixed,
// in-window) + edge ~25 (VALU floor 7.5, L2 floor 7.4) + pq ~10 + gaps ~15-20
// (harness). Five single-mechanism theories each bought <=2us; marginal yield
// < noise (+-1us). This is the practical floor for this harness.

#define H  128
#define NI 20000
#define NC 10000
#define NE 1000000

typedef _Float16 half8   __attribute__((ext_vector_type(8)));
typedef _Float16 half2   __attribute__((ext_vector_type(2)));
typedef float    floatx2 __attribute__((ext_vector_type(2)));
typedef float    floatx4 __attribute__((ext_vector_type(4)));

// ws byte layout
#define P8_OFF    0
#define Q8_OFF    (NI * H)                    // 2,560,000
// total ws use: 3,840,000 B (P8 + Q8)

#define PB (NI / 16)   // 1250 strips of P
#define QB (NC / 16)   // 625 strips of Q
#define NSTRIP 4
#define PBLKS ((PB + NSTRIP - 1) / NSTRIP)    // 313
#define QBLKS ((QB + NSTRIP - 1) / NSTRIP)    // 157

// ---------- fp8 e4m3 helpers (HW path on gfx950; SW fallback for safety) ----
#if __has_builtin(__builtin_amdgcn_cvt_pk_f32_fp8) && __has_builtin(__builtin_amdgcn_cvt_pk_fp8_f32)
#define HW_FP8 1
#else
#define HW_FP8 0
__device__ inline unsigned char enc_e4m3(float x) {
    unsigned s = x < 0.0f ? 0x80u : 0u;
    float a = fminf(fabsf(x), 448.0f);
    if (a < 0.0009765625f) return (unsigned char)s;       // < 2^-10 -> 0
    int e; float m = frexpf(a, &e);                       // a = m*2^e, m in [0.5,1)
    int E = e + 6;                                        // biased exp
    if (E <= 0) {                                         // subnormal: f*2^-9
        int f = (int)rintf(a * 512.0f);
        if (f > 7) return (unsigned char)(s | 0x08);
        return (unsigned char)(s | f);
    }
    int f = (int)rintf((m * 2.0f - 1.0f) * 8.0f);
    if (f == 8) { f = 0; ++E; }
    if (E > 15 || (E == 15 && f > 6)) { E = 15; f = 6; }  // clamp to 448
    return (unsigned char)(s | (E << 3) | f);
}
__device__ inline float dec_e4m3(unsigned char b) {
    int E = (b >> 3) & 15, f = b & 7;
    float v = (E == 0) ? (float)f * 0.001953125f          // f * 2^-9
                       : (float)(8 + f) * exp2f((float)(E - 10));
    return (b & 0x80) ? -v : v;
}
#endif

// f16 fast path: fp8->f16 packed decode + dot2 f16 MAC with f32 accumulate
#if HW_FP8 && __has_builtin(__builtin_amdgcn_cvt_pk_f16_fp8) && __has_builtin(__builtin_amdgcn_fdot2)
#define HW_F16 1
__device__ __forceinline__ half2 dec2h(short s) {
    auto t = __builtin_amdgcn_cvt_pk_f16_fp8(s);
    half2 r; __builtin_memcpy(&r, &t, sizeof(r)); return r;
}
__device__ __forceinline__ half2 hrelu2(half2 v) {
#if __has_builtin(__builtin_elementwise_max)
    half2 z = {(_Float16)0.0f, (_Float16)0.0f};
    return __builtin_elementwise_max(v, z);
#else
    half2 r = { v.x > (_Float16)0.0f ? v.x : (_Float16)0.0f,
                v.y > (_Float16)0.0f ? v.y : (_Float16)0.0f };
    return r;
#endif
}
#else
#define HW_F16 0
#endif

__device__ inline floatx2 relu2(floatx2 v) {
#if __has_builtin(__builtin_elementwise_max)
    floatx2 z = {0.0f, 0.0f};
    return __builtin_elementwise_max(v, z);
#else
    floatx2 r = { fmaxf(v.x, 0.0f), fmaxf(v.y, 0.0f) };
    return r;
#endif
}

__device__ __forceinline__ float fast_sigmoid(float x) {
#if __has_builtin(__builtin_amdgcn_exp2f) && __has_builtin(__builtin_amdgcn_rcpf)
    const float t = __builtin_amdgcn_exp2f(-1.4426950408889634f * x);
    return __builtin_amdgcn_rcpf(1.0f + t);
#else
    return 1.0f / (1.0f + __expf(-x));
#endif
}

// DPP-fused butterfly add over 8-lane groups (no LDS pipe, no lgkmcnt)
#if __has_builtin(__builtin_amdgcn_update_dpp)
template <int CTRL>
__device__ __forceinline__ float dpp_add(float x) {
    const int yi = __builtin_amdgcn_update_dpp(0, __float_as_int(x), CTRL, 0xf, 0xf, false);
    return x + __int_as_float(yi);
}
#define REDUCE8(ACC) do {                          \
        ACC = dpp_add<0xB1>(ACC);  /* quad_perm [1,0,3,2] : xor1 */        \
        ACC = dpp_add<0x4E>(ACC);  /* quad_perm [2,3,0,1] : xor2 */        \
        ACC = dpp_add<0x141>(ACC); /* row_half_mirror     : xor4 */        \
    } while (0)
#else
#define REDUCE8(ACC) do {                          \
        ACC += __shfl_xor(ACC, 1);                 \
        ACC += __shfl_xor(ACC, 2);                 \
        ACC += __shfl_xor(ACC, 4);                 \
    } while (0)
#endif

// ---------- P/Q precompute: direct W1 fragments, 4 strips/block (r15) -------
__launch_bounds__(256)
__global__ void pq_gemm(const float* __restrict__ xin,
                        const float* __restrict__ xcmp,
                        const float* __restrict__ b1,
                        const float* __restrict__ W1,   // [256][128] row-major
                        unsigned char* __restrict__ wsb) {
    const int b    = blockIdx.x;
    const bool isQ = (b >= PBLKS);
    const int  sb  = isQ ? b - PBLKS : b;
    const int  s0  = sb * NSTRIP;                 // first strip of this block
    const int  smax = (isQ ? QB : PB) - 1;        // last valid strip
    const float* X = isQ ? xcmp : xin;
    unsigned char* OUT8 = wsb + (isQ ? Q8_OFF : P8_OFF);

    const int lane = threadIdx.x & 63;
    const int w    = threadIdx.x >> 6;
    const int quad = lane >> 4;
    const int m    = lane & 15;

    // B-fragments straight from W1, ONCE per block (amortized over 4 strips)
    half8 bf[2][4];
    float b1v[2];
#pragma unroll
    for (int nt = 0; nt < 2; ++nt) {
        const int n = w * 32 + nt * 16 + m;
#pragma unroll
        for (int ks = 0; ks < 4; ++ks) {
            const float* wp = W1 + (long)(isQ * 128 + ks * 32 + quad * 8) * H + n;
            half8 v;
#pragma unroll
            for (int j = 0; j < 8; ++j)
                v[j] = (_Float16)wp[j * H];
            bf[nt][ks] = v;
        }
        b1v[nt] = isQ ? b1[n] : 0.0f;
    }

#define LOADA(S, AF) do {                                                \
        const int _s = (S) > smax ? smax : (S);                          \
        const float* xr = X + (long)(_s * 16 + m) * H + quad * 8;        \
        _Pragma("unroll")                                                \
        for (int ks = 0; ks < 4; ++ks) {                                 \
            float4 a = *(const float4*)(xr + ks * 32);                   \
            float4 c = *(const float4*)(xr + ks * 32 + 4);               \
            half8 v = { (_Float16)a.x, (_Float16)a.y, (_Float16)a.z,     \
                        (_Float16)a.w, (_Float16)c.x, (_Float16)c.y,     \
                        (_Float16)c.z, (_Float16)c.w };                  \
            AF[ks] = v;                                                  \
        }                                                                \
    } while (0)

#if HW_FP8
#define EMIT8(PTR, V) do {                                               \
        const unsigned _u = (unsigned)__builtin_amdgcn_cvt_pk_fp8_f32((V), (V), 0, false); \
        *(unsigned char*)(PTR) = (unsigned char)(_u & 0xff);             \
    } while (0)
#else
#define EMIT8(PTR, V) do { *(unsigned char*)(PTR) = enc_e4m3(V); } while (0)
#endif

#define STRIPC(S, AF) do {                                               \
        floatx4 acc[2] = { (floatx4)0.0f, (floatx4)0.0f };               \
        _Pragma("unroll")                                                \
        for (int ks = 0; ks < 4; ++ks)                                   \
            _Pragma("unroll")                                            \
            for (int nt = 0; nt < 2; ++nt)                               \
                acc[nt] = __builtin_amdgcn_mfma_f32_16x16x32_f16(        \
                              AF[ks], bf[nt][ks], acc[nt], 0, 0, 0);     \
        if ((S) <= smax) {                                               \
            const int rb = (S) * 16;                                     \
            _Pragma("unroll")                                            \
            for (int nt = 0; nt < 2; ++nt) {                             \
                const int col = w * 32 + nt * 16 + m;                    \
                _Pragma("unroll")                                        \
                for (int r = 0; r < 4; ++r) {                            \
                    const float v = acc[nt][r] + b1v[nt];                \
                    EMIT8(OUT8 + (rb + quad * 4 + r) * H + col, v);      \
                }                                                        \
            }                                                            \
        }                                                                \
    } while (0)

    half8 afA[4], afB[4];
    LOADA(s0, afA);
    LOADA(s0 + 1, afB);
    STRIPC(s0,     afA);
    LOADA(s0 + 2, afA);
    STRIPC(s0 + 1, afB);
    LOADA(s0 + 3, afB);
    STRIPC(s0 + 2, afA);
    STRIPC(s0 + 3, afB);

#undef LOADA
#undef STRIPC
#undef EMIT8
}

// ---------- edge kernel: 8 lanes/edge, FULL 16-pass unroll, f16 inner math --
#define EGRID 2048
#define ESTEP (32 * EGRID)          // 65536 edges per device pass
// NE = 1,000,000 = 15 full passes (k=0..14) + tail pass k=15 (16,960 edges)

__launch_bounds__(256)
__global__ void edge_mlp(const unsigned char* __restrict__ wsb,
                         const int* __restrict__ src_idx,
                         const int* __restrict__ dst_idx,
                         const float* __restrict__ W2,
                         const float* __restrict__ b2p,
                         float* __restrict__ out) {
    const int tid  = threadIdx.x;
    const int c    = tid & 7;       // 16-byte slice of the 128-B row
    const int slot = tid >> 3;      // edge within block-pass (0..31)

    // W2 slice: 16 coefficients for cols c*16..c*16+15
#if HW_F16
    half2 w2h[8];
#pragma unroll
    for (int i = 0; i < 8; ++i) {
        floatx2 f = *(const floatx2*)(W2 + c * 16 + i * 2);
        half2 h = { (_Float16)f.x, (_Float16)f.y };
        w2h[i] = h;
    }
#else
    floatx2 w2v[8];
#pragma unroll
    for (int i = 0; i < 8; ++i) w2v[i] = *(const floatx2*)(W2 + c * 16 + i * 2);
#endif
    const float b2v = b2p[0];

    const unsigned char* P8 = wsb + P8_OFF;
    const unsigned char* Q8 = wsb + Q8_OFF;
    const int ebase = blockIdx.x * 32 + slot;   // < 65536

    int  si[16], di[16];
    uint4 pd[16], qd[16];

    // idx load: only k=15 can run past NE (clamped; its store is masked)
#define LDIDX(K) do {                                                \
        int _e = ebase + (K) * ESTEP;                                \
        if ((K) == 15) _e = _e < NE ? _e : NE - 1;                   \
        si[K] = __builtin_nontemporal_load(src_idx + _e);            \
        di[K] = __builtin_nontemporal_load(dst_idx + _e);            \
    } while (0)

#define ISSUE(K) do {                                                \
        pd[K] = *(const uint4*)(P8 + si[K] * H + c * 16);            \
        qd[K] = *(const uint4*)(Q8 + di[K] * H + c * 16);            \
    } while (0)

#if HW_F16
    // f16 path: 4 dec + 2 pk_add + 2 pk_max + 2 fdot2 per word, all full-rate
#define INNER(PW, QW, JW, ACC) do {                                  \
        half2 pl = dec2h((short)(PW));                               \
        half2 ph = dec2h((short)((PW) >> 16));                       \
        half2 ql = dec2h((short)(QW));                               \
        half2 qh = dec2h((short)((QW) >> 16));                       \
        half2 hl = hrelu2(pl + ql);                                  \
        half2 hh = hrelu2(ph + qh);                                  \
        ACC = __builtin_amdgcn_fdot2(hl, w2h[2 * (JW)], ACC, false); \
        ACC = __builtin_amdgcn_fdot2(hh, w2h[2 * (JW) + 1], ACC, false); \
    } while (0)
#define COMPUTE(K) do {                                              \
        float acc = 0.0f;                                            \
        const unsigned pw[4] = { pd[K].x, pd[K].y, pd[K].z, pd[K].w }; \
        const unsigned qw[4] = { qd[K].x, qd[K].y, qd[K].z, qd[K].w }; \
        _Pragma("unroll")                                            \
        for (int jw = 0; jw < 4; ++jw)                               \
            INNER(pw[jw], qw[jw], jw, acc);                          \
        REDUCE8(acc);                                                \
        const float r = fast_sigmoid(acc + b2v);                     \
        const int _e = ebase + (K) * ESTEP;                          \
        if (c == 0 && ((K) < 15 || _e < NE))                         \
            __builtin_nontemporal_store(r, out + _e);                \
    } while (0)
#else
    // f32 fallback (proven r17 path)
#if HW_FP8
#define DECODE(PW, QW, PL, PH, QL, QH) do {                          \
        PL = __builtin_amdgcn_cvt_pk_f32_fp8((int)(PW), false);      \
        PH = __builtin_amdgcn_cvt_pk_f32_fp8((int)(PW), true);       \
        QL = __builtin_amdgcn_cvt_pk_f32_fp8((int)(QW), false);      \
        QH = __builtin_amdgcn_cvt_pk_f32_fp8((int)(QW), true);       \
    } while (0)
#else
#define DECODE(PW, QW, PL, PH, QL, QH) do {                          \
        PL = { dec_e4m3((PW) & 0xff), dec_e4m3(((PW) >> 8) & 0xff) };  \
        PH = { dec_e4m3(((PW) >> 16) & 0xff), dec_e4m3((PW) >> 24) };  \
        QL = { dec_e4m3((QW) & 0xff), dec_e4m3(((QW) >> 8) & 0xff) };  \
        QH = { dec_e4m3(((QW) >> 16) & 0xff), dec_e4m3((QW) >> 24) };  \
    } while (0)
#endif
#define COMPUTE(K) do {                                              \
        floatx2 acc2 = {0.0f, 0.0f};                                 \
        const unsigned pw[4] = { pd[K].x, pd[K].y, pd[K].z, pd[K].w }; \
        const unsigned qw[4] = { qd[K].x, qd[K].y, qd[K].z, qd[K].w }; \
        _Pragma("unroll")                                            \
        for (int jw = 0; jw < 4; ++jw) {                             \
            floatx2 pl, ph, ql, qh;                                  \
            DECODE(pw[jw], qw[jw], pl, ph, ql, qh);                  \
            acc2 += relu2(pl + ql) * w2v[2 * jw];                    \
            acc2 += relu2(ph + qh) * w2v[2 * jw + 1];                \
        }                                                            \
        float acc = acc2.x + acc2.y;                                 \
        REDUCE8(acc);                                                \
        const float r = fast_sigmoid(acc + b2v);                     \
        const int _e = ebase + (K) * ESTEP;                          \
        if (c == 0 && ((K) < 15 || _e < NE))                         \
            __builtin_nontemporal_store(r, out + _e);                \
    } while (0)
#endif

    // ---- software pipeline (fully unrolled; all indices compile-time) ----
    // idx 8 passes ahead, rows 4 passes ahead (~500cy + multi-wave overlap)
#pragma unroll
    for (int k = 0; k < 8; ++k) LDIDX(k);
#pragma unroll
    for (int k = 0; k < 4; ++k) ISSUE(k);
#pragma unroll
    for (int k = 0; k < 16; ++k) {
        if (k + 4 < 16) ISSUE(k + 4);
        if (k + 8 < 16) LDIDX(k + 8);
        COMPUTE(k);
    }

#undef LDIDX
#undef ISSUE
#undef COMPUTE
}

extern "C" void kernel_launch(void* const* d_in, const int* in_sizes, int n_in,
                              void* d_out, int out_size, void* d_ws, size_t ws_size,
                              hipStream_t stream) {
    const float* xin  = (const float*)d_in[0];
    const float* xcmp = (const float*)d_in[1];
    const int*   eidx = (const int*)d_in[2];    // [2,E]: first E src, next E dst
    const float* W1   = (const float*)d_in[3];
    const float* b1   = (const float*)d_in[4];
    const float* W2   = (const float*)d_in[5];
    const float* b2   = (const float*)d_in[6];
    float* out = (float*)d_out;
    unsigned char* wsb = (unsigned char*)d_ws;  // 3.84 MB used

    hipLaunchKernelGGL(pq_gemm, dim3(PBLKS + QBLKS), dim3(256), 0, stream,
                       xin, xcmp, b1, W1, wsb);
    hipLaunchKernelGGL(edge_mlp, dim3(EGRID), dim3(256), 0, stream,
                       wsb, eidx, eidx + NE, W2, b2, out);
}